// Round 1
// baseline (84.909 us; speedup 1.0000x reference)
//
#include <hip/hip_runtime.h>
#include <math.h>

// x: (32,1,512,512) f32 -> out: (32,64,64,64) f32
// One thread per 8x8 spatial block. k = u*5+v for u in [0,8), v in [0,5);
// channels 40..63 are zero.

#define NBLOCKS (32 * 64 * 64)   // 131072 threads total

__global__ __launch_bounds__(256) void dct_kernel(
    const float* __restrict__ x,
    const float* __restrict__ fw,
    float* __restrict__ out)
{
    __shared__ float wsig[40];
    const int tid = threadIdx.x;
    if (tid < 40) {
        float f = fw[tid];
        wsig[tid] = 1.0f / (1.0f + __expf(-f));
    }
    __syncthreads();

    const int gid = blockIdx.x * 256 + tid;       // 0 .. 131071
    const int wb = gid & 63;
    const int hb = (gid >> 6) & 63;
    const int b  = gid >> 12;

    const float* xp = x + ((size_t)b * 512 + (size_t)hb * 8) * 512 + (size_t)wb * 8;

    // Twiddle tables: exp(-i*2*pi*t/8) = ct[t] - i*st[t]
    const float R = 0.70710678118654752440f;
    const float ct[8] = {1.0f,  R, 0.0f, -R, -1.0f, -R,  0.0f,  R};
    const float st[8] = {0.0f,  R, 1.0f,  R,  0.0f, -R, -1.0f, -R};

    float dr[8][5], di[8][5];
    #pragma unroll
    for (int u = 0; u < 8; ++u)
        #pragma unroll
        for (int v = 0; v < 5; ++v) { dr[u][v] = 0.0f; di[u][v] = 0.0f; }

    #pragma unroll
    for (int i = 0; i < 8; ++i) {
        const float4 a  = *reinterpret_cast<const float4*>(xp + (size_t)i * 512);
        const float4 c4 = *reinterpret_cast<const float4*>(xp + (size_t)i * 512 + 4);
        const float row[8] = {a.x, a.y, a.z, a.w, c4.x, c4.y, c4.z, c4.w};

        // Row rfft: c[v] = sum_j row[j] * exp(-i*2pi*v*j/8), v = 0..4
        float cr[5], ci[5];
        #pragma unroll
        for (int v = 0; v < 5; ++v) {
            float sr = 0.0f, si = 0.0f;
            #pragma unroll
            for (int j = 0; j < 8; ++j) {
                const int t = (v * j) & 7;
                sr += row[j] * ct[t];
                si -= row[j] * st[t];
            }
            cr[v] = sr; ci[v] = si;
        }

        // Column DFT accumulate: d[u][v] += c[v] * exp(-i*2pi*u*i/8)
        #pragma unroll
        for (int u = 0; u < 8; ++u) {
            const int t = (u * i) & 7;
            const float wr = ct[t];
            const float wi = -st[t];
            #pragma unroll
            for (int v = 0; v < 5; ++v) {
                dr[u][v] += cr[v] * wr - ci[v] * wi;
                di[u][v] += cr[v] * wi + ci[v] * wr;
            }
        }
    }

    // out[b][k][hb][wb], plane stride 64*64 = 4096
    float* op = out + (((size_t)b * 64) * 64 + (size_t)hb) * 64 + wb;
    #pragma unroll
    for (int u = 0; u < 8; ++u) {
        #pragma unroll
        for (int v = 0; v < 5; ++v) {
            const int k = u * 5 + v;
            const float mag =
                sqrtf(dr[u][v] * dr[u][v] + di[u][v] * di[u][v]) * 0.125f * wsig[k];
            op[(size_t)k * 4096] = mag;
        }
    }
    #pragma unroll
    for (int k = 40; k < 64; ++k) {
        op[(size_t)k * 4096] = 0.0f;
    }
}

extern "C" void kernel_launch(void* const* d_in, const int* in_sizes, int n_in,
                              void* d_out, int out_size, void* d_ws, size_t ws_size,
                              hipStream_t stream)
{
    const float* x  = (const float*)d_in[0];
    const float* fw = (const float*)d_in[1];
    float* out = (float*)d_out;

    dct_kernel<<<dim3(NBLOCKS / 256), dim3(256), 0, stream>>>(x, fw, out);
}

// Round 7
// 84.008 us; speedup vs baseline: 1.0107x; 1.0107x over previous
//
#include <hip/hip_runtime.h>
#include <math.h>

// x: (32,1,512,512) f32 -> out: (32,64,64,64) f32
// Workgroup (256 thr) per (b, hb): handles 64 blocks (wb=0..63).
// Phase A: thread (wb, r) row-rfft of 8 floats -> 8 nonzero spectra floats in LDS.
// Phase B: thread (wb, u0) column DFT for u = u0 and u0+4 (shared products),
//          compile-time twiddles via wave-uniform branch on u0.

#define R8 0.70710678118654752440f

__global__ __launch_bounds__(256, 4) void dct_kernel(
    const float* __restrict__ x,
    const float* __restrict__ fw,
    float* __restrict__ out)
{
    __shared__ float spec[64 * 65];   // pitch 65 (odd) -> conflict-free b32
    __shared__ float wsig[40];

    const int tid = threadIdx.x;
    const int g   = blockIdx.x;       // 0..2047
    const int b   = g >> 6;
    const int hb  = g & 63;

    if (tid < 40) {
        float f = fw[tid];
        wsig[tid] = 1.0f / (1.0f + __expf(-f));
    }

    const int wb = tid & 63;
    const int rr = tid >> 6;          // 0..3, wave-uniform

    // ---------------- Phase A: row FFTs ----------------
    #pragma unroll
    for (int s = 0; s < 2; ++s) {
        const int r = rr + 4 * s;
        const float* xp = x + (((size_t)b * 512) + (size_t)hb * 8 + r) * 512 + (size_t)wb * 8;
        const float4 A = *reinterpret_cast<const float4*>(xp);
        const float4 Bv = *reinterpret_cast<const float4*>(xp + 4);
        const float r0 = A.x, r1 = A.y, r2 = A.z, r3 = A.w;
        const float r4 = Bv.x, r5 = Bv.y, r6 = Bv.z, r7 = Bv.w;

        const float a04p = r0 + r4, a04m = r0 - r4;
        const float a26p = r2 + r6, a26m = r2 - r6;
        const float a15p = r1 + r5, a15m = r1 - r5;
        const float a37p = r3 + r7, a37m = r3 - r7;

        const float s1 = a04p + a26p, s2 = a15p + a37p;
        const float t1 = R8 * (a15m - a37m);
        const float t2 = R8 * (a15m + a37m);

        const float cr0 = s1 + s2;
        const float cr4 = s1 - s2;
        const float cr2 = a04p - a26p;
        const float ci2 = a37p - a15p;
        const float cr1 = a04m + t1;
        const float cr3 = a04m - t1;
        const float ci1 = -(a26m + t2);
        const float ci3 = a26m - t2;

        float* sp = &spec[wb * 65 + r * 8];
        sp[0] = cr0;
        sp[1] = cr1; sp[2] = ci1;
        sp[3] = cr2; sp[4] = ci2;
        sp[5] = cr3; sp[6] = ci3;
        sp[7] = cr4;
    }

    __syncthreads();

    // ---------------- Phase B: column DFTs for u = rr and rr+4 ----------------
    const float* sp = &spec[wb * 65];

    float dAr[5], dAi[5], dBr[5], dBi[5];
    #pragma unroll
    for (int v = 0; v < 5; ++v) { dAr[v] = dAi[v] = dBr[v] = dBi[v] = 0.0f; }

#define COL_I(i, CW, SW) do {                                                  \
    const float c0r = sp[(i)*8+0];                                             \
    const float c1r = sp[(i)*8+1], c1i = sp[(i)*8+2];                          \
    const float c2r = sp[(i)*8+3], c2i = sp[(i)*8+4];                          \
    const float c3r = sp[(i)*8+5], c3i = sp[(i)*8+6];                          \
    const float c4r = sp[(i)*8+7];                                             \
    const float cw = (CW), sw = (SW);                                          \
    const float t0r = c0r*cw;              const float t0i = c0r*sw;           \
    const float t1r = c1r*cw - c1i*sw;     const float t1i = c1r*sw + c1i*cw;  \
    const float t2r = c2r*cw - c2i*sw;     const float t2i = c2r*sw + c2i*cw;  \
    const float t3r = c3r*cw - c3i*sw;     const float t3i = c3r*sw + c3i*cw;  \
    const float t4r = c4r*cw;              const float t4i = c4r*sw;           \
    dAr[0] += t0r; dAi[0] += t0i; dAr[1] += t1r; dAi[1] += t1i;                \
    dAr[2] += t2r; dAi[2] += t2i; dAr[3] += t3r; dAi[3] += t3i;                \
    dAr[4] += t4r; dAi[4] += t4i;                                              \
    if ((i) & 1) {                                                             \
        dBr[0] -= t0r; dBi[0] -= t0i; dBr[1] -= t1r; dBi[1] -= t1i;            \
        dBr[2] -= t2r; dBi[2] -= t2i; dBr[3] -= t3r; dBi[3] -= t3i;            \
        dBr[4] -= t4r; dBi[4] -= t4i;                                          \
    } else {                                                                   \
        dBr[0] += t0r; dBi[0] += t0i; dBr[1] += t1r; dBi[1] += t1i;            \
        dBr[2] += t2r; dBi[2] += t2i; dBr[3] += t3r; dBi[3] += t3i;            \
        dBr[4] += t4r; dBi[4] += t4i;                                          \
    }                                                                          \
} while (0)

    // Wave-uniform branch: rr = tid>>6 is constant within each wave.
    if (rr == 0) {
        COL_I(0, 1.0f, 0.0f); COL_I(1, 1.0f, 0.0f);
        COL_I(2, 1.0f, 0.0f); COL_I(3, 1.0f, 0.0f);
        COL_I(4, 1.0f, 0.0f); COL_I(5, 1.0f, 0.0f);
        COL_I(6, 1.0f, 0.0f); COL_I(7, 1.0f, 0.0f);
    } else if (rr == 1) {
        COL_I(0, 1.0f, 0.0f);  COL_I(1,  R8, -R8);
        COL_I(2, 0.0f, -1.0f); COL_I(3, -R8, -R8);
        COL_I(4, -1.0f, 0.0f); COL_I(5, -R8,  R8);
        COL_I(6, 0.0f, 1.0f);  COL_I(7,  R8,  R8);
    } else if (rr == 2) {
        COL_I(0, 1.0f, 0.0f);  COL_I(1, 0.0f, -1.0f);
        COL_I(2, -1.0f, 0.0f); COL_I(3, 0.0f, 1.0f);
        COL_I(4, 1.0f, 0.0f);  COL_I(5, 0.0f, -1.0f);
        COL_I(6, -1.0f, 0.0f); COL_I(7, 0.0f, 1.0f);
    } else {
        COL_I(0, 1.0f, 0.0f);  COL_I(1, -R8, -R8);
        COL_I(2, 0.0f, 1.0f);  COL_I(3,  R8, -R8);
        COL_I(4, -1.0f, 0.0f); COL_I(5,  R8,  R8);
        COL_I(6, 0.0f, -1.0f); COL_I(7, -R8,  R8);
    }
#undef COL_I

    // ---------------- Stores ----------------
    // out[b][k][hb][wb]; plane stride 4096 floats. Wave = fixed u -> 64
    // consecutive wb per store (256 B contiguous).
    float* op = out + ((size_t)b * 64) * 4096 + (size_t)hb * 64 + wb;

    const int uA = rr;          // k = uA*5+v
    const int uB = rr + 4;      // k = uB*5+v
    #pragma unroll
    for (int v = 0; v < 5; ++v) {
        const int kA = uA * 5 + v;
        const float magA = sqrtf(dAr[v] * dAr[v] + dAi[v] * dAi[v]) * 0.125f * wsig[kA];
        op[(size_t)kA * 4096] = magA;
    }
    #pragma unroll
    for (int v = 0; v < 5; ++v) {
        const int kB = uB * 5 + v;
        const float magB = sqrtf(dBr[v] * dBr[v] + dBi[v] * dBi[v]) * 0.125f * wsig[kB];
        op[(size_t)kB * 4096] = magB;
    }
    // Zero planes 40..63: wave u0 handles k = 40 + u0*6 + {0..5}
    #pragma unroll
    for (int m = 0; m < 6; ++m) {
        const int k = 40 + rr * 6 + m;
        op[(size_t)k * 4096] = 0.0f;
    }
}

extern "C" void kernel_launch(void* const* d_in, const int* in_sizes, int n_in,
                              void* d_out, int out_size, void* d_ws, size_t ws_size,
                              hipStream_t stream)
{
    const float* x  = (const float*)d_in[0];
    const float* fw = (const float*)d_in[1];
    float* out = (float*)d_out;

    dct_kernel<<<dim3(32 * 64), dim3(256), 0, stream>>>(x, fw, out);
}